// Round 3
// baseline (530.654 us; speedup 1.0000x reference)
//
#include <hip/hip_runtime.h>

// ---------------------------------------------------------------------------
// Linformer self-attention, MI355X (gfx950).  Round 6.
//   Gt = Wq*Wk^T;  Mt[b] = Pk[b]*Gt^T/32 + sk(x)h;  scores = x*Mt^T + cb[b]
//   R4: fast 64x64 transpose; scores GEMM fused with softmax (128x256 tile);
//       kv merged into M-dim of the Pkv GEMM.
//   R5: tr64 conflict-free (pitch-65 LDS); colsum2 128 blocks.
//       [post-mortem: tr64 is memory-system-bound at ~3.3 TB/s app traffic,
//        NOT conflict-bound — conflicts 7.3e6->2.1e6 with zero time change]
//   R6: P32 K-split + fp32 round-trip ELIMINATED — single-pass K=4096 GEMM
//       accumulates in fp32 regs, writes f16 Pkv directly (saves ~150 MB HBM,
//       removes reduce_kv dispatch). Pkv relaid [8b][512(k|v)][1024].
//       Final out-GEMM uses nontemporal stores (out is never re-read).
// Generic gemm_bt: 128x128 tile, BK=64, global_load_lds width-16,
// ds_read_b128 frags, XCD panel swizzle, XOR bank swizzle (0 conflicts, R2).
// fp16 (not bf16): softmax is near-argmax; bf16 score noise fails threshold.
// ---------------------------------------------------------------------------

typedef __attribute__((ext_vector_type(8))) _Float16 half8;
typedef __attribute__((ext_vector_type(4))) _Float16 half4;
typedef __attribute__((ext_vector_type(4))) float f32x4;

#define AS1 __attribute__((address_space(1)))
#define AS3 __attribute__((address_space(3)))

__device__ __forceinline__ void gld_lds16(const void* g, void* l) {
    __builtin_amdgcn_global_load_lds((AS1 void*)g, (AS3 void*)l, 16, 0, 0);
}

template <typename T> struct is_f32 { static constexpr bool v = false; };
template <> struct is_f32<float> { static constexpr bool v = true; };

template <typename T> __device__ __forceinline__ T to_out(float v);
template <> __device__ __forceinline__ float    to_out<float>(float v) { return v; }
template <> __device__ __forceinline__ _Float16 to_out<_Float16>(float v) { return (_Float16)v; }

// ---------------------------------------------------------------------------
// C[m,n] = scale * sum_k A[m,k]*B[n,k] (+bias[n], batched by sb0) (+rowv[m]*colv[n])
// float outputs use nontemporal stores (only the final `out` GEMM emits fp32).
// ---------------------------------------------------------------------------
template <typename OUT_T, bool SWIZ>
__global__ __launch_bounds__(256) void gemm_bt(
    const _Float16* __restrict__ A, long sA0, long sA1, long sA2, int lda,
    const _Float16* __restrict__ B, long sB0, long sB1, long sB2, int ldb,
    OUT_T* __restrict__ C, long sC0, long sC1, long sC2, int ldc,
    int nz0, int nz1, int NM, int NN, int Kd,
    const float* __restrict__ bias, long sb0,
    const float* __restrict__ rowv, const float* __restrict__ colv, float scale)
{
    {   // z-decode: 3-level batching
        const int z = blockIdx.z;
        const int z0 = z % nz0, t = z / nz0, z1 = t % nz1, z2 = t / nz1;
        A += z0 * sA0 + z1 * sA1 + z2 * sA2;
        B += z0 * sB0 + z1 * sB1 + z2 * sB2;
        C += z0 * sC0 + z1 * sC1 + z2 * sC2;
        if (bias) bias += (long)z0 * sb0;
    }
    int mb, nb;
    if (SWIZ) {  // requires NM % 8 == 0: XCD keeps one A-panel hot
        const int g = blockIdx.x, r = g % (8 * NN);
        mb = (g / (8 * NN)) * 8 + (r & 7);
        nb = r >> 3;
    } else {
        mb = blockIdx.x % NM;
        nb = blockIdx.x / NM;
    }
    const int tid = threadIdx.x, w = tid >> 6, ln = tid & 63;
    const int wm = (w >> 1) * 64, wn = (w & 1) * 64;

    __shared__ __attribute__((aligned(16))) _Float16 As[128 * 64];
    __shared__ __attribute__((aligned(16))) _Float16 Bs[128 * 64];

    f32x4 acc[4][4] = {};

    const int cb0 = w * 256;
    const _Float16* Ablk = A + (long)mb * 128 * lda;
    const _Float16* Bblk = B + (long)nb * 128 * ldb;

    const int lr = ln & 15, rs = ln & 7, kq = ln >> 4;

    for (int k0 = 0; k0 < Kd; k0 += 64) {
#pragma unroll
        for (int t = 0; t < 4; ++t) {
            const int ci = cb0 + t * 64 + ln;
            const int r = ci >> 3, kc = (ci & 7) ^ (r & 7);
            gld_lds16(Ablk + (long)r * lda + k0 + kc * 8, &As[(cb0 + t * 64) * 8]);
            gld_lds16(Bblk + (long)r * ldb + k0 + kc * 8, &Bs[(cb0 + t * 64) * 8]);
        }
        __syncthreads();
#pragma unroll
        for (int kh = 0; kh < 2; ++kh) {
            const int c = (((kh * 4) + kq) ^ rs) * 8;
            half8 af[4], bf[4];
#pragma unroll
            for (int i = 0; i < 4; ++i) {
                af[i] = *(const half8*)&As[(wm + i * 16 + lr) * 64 + c];
                bf[i] = *(const half8*)&Bs[(wn + i * 16 + lr) * 64 + c];
            }
#pragma unroll
            for (int i = 0; i < 4; ++i)
#pragma unroll
                for (int j = 0; j < 4; ++j)
                    acc[i][j] = __builtin_amdgcn_mfma_f32_16x16x32_f16(af[i], bf[j], acc[i][j], 0, 0, 0);
        }
        __syncthreads();
    }

    // C/D layout: col = lane&15, row = (lane>>4)*4 + reg
    const int crow = mb * 128 + wm + (kq << 2);
    const int ccol = nb * 128 + wn + lr;
#pragma unroll
    for (int i = 0; i < 4; ++i)
#pragma unroll
        for (int r = 0; r < 4; ++r) {
            const long row = crow + i * 16 + r;
#pragma unroll
            for (int j = 0; j < 4; ++j) {
                const int col = ccol + j * 16;
                float v = acc[i][j][r] * scale;
                if (bias) v += bias[col];
                if (rowv) v += rowv[row] * colv[col];
                if constexpr (is_f32<OUT_T>::v)
                    __builtin_nontemporal_store(v, &C[row * ldc + col]);
                else
                    C[row * ldc + col] = to_out<OUT_T>(v);
            }
        }
}

// ---------------------------------------------------------------------------
// Fused scores+softmax: wts[b][l][kk] = softmax_kk( x[b][l]:Mt[b][kk] + cb[b][kk] )
// Block = 128 rows x 256 cols (full kk range). Wave = 32 rows x 256 cols.
// ---------------------------------------------------------------------------
__global__ __launch_bounds__(256) void score_softmax(
    const _Float16* __restrict__ A, const _Float16* __restrict__ Bm,
    const float* __restrict__ cb, _Float16* __restrict__ Wts)
{
    const int b = blockIdx.z, mb = blockIdx.x;
    const _Float16* Ab = A + (long)b * 4194304 + (long)mb * 131072;
    const _Float16* Bb = Bm + (long)b * 262144;
    const int tid = threadIdx.x, w = tid >> 6, ln = tid & 63;
    const int lr = ln & 15, rs = ln & 7, kq = ln >> 4;

    __shared__ __attribute__((aligned(16))) _Float16 SM[24576]; // As 8192 | Bs 16384
    _Float16* As = SM;
    _Float16* Bs = SM + 8192;

    f32x4 acc[2][16] = {};

    for (int k0 = 0; k0 < 1024; k0 += 64) {
#pragma unroll
        for (int t = 0; t < 4; ++t) {           // A-tile: 128x64
            const int cbase = w * 256 + t * 64;
            const int ci = cbase + ln, r = ci >> 3, kc = (ci & 7) ^ (r & 7);
            gld_lds16(Ab + (long)r * 1024 + k0 + kc * 8, &As[cbase * 8]);
        }
#pragma unroll
        for (int t = 0; t < 8; ++t) {           // B-tile: 256x64
            const int cbase = w * 512 + t * 64;
            const int ci = cbase + ln, r = ci >> 3, kc = (ci & 7) ^ (r & 7);
            gld_lds16(Bb + (long)r * 1024 + k0 + kc * 8, &Bs[cbase * 8]);
        }
        __syncthreads();
#pragma unroll
        for (int kh = 0; kh < 2; ++kh) {
            const int c = (((kh * 4) + kq) ^ rs) * 8;
            const half8 af0 = *(const half8*)&As[(w * 32 + lr) * 64 + c];
            const half8 af1 = *(const half8*)&As[(w * 32 + 16 + lr) * 64 + c];
#pragma unroll
            for (int j = 0; j < 16; ++j) {
                const half8 bf = *(const half8*)&Bs[(j * 16 + lr) * 64 + c];
                acc[0][j] = __builtin_amdgcn_mfma_f32_16x16x32_f16(af0, bf, acc[0][j], 0, 0, 0);
                acc[1][j] = __builtin_amdgcn_mfma_f32_16x16x32_f16(af1, bf, acc[1][j], 0, 0, 0);
            }
        }
        __syncthreads();
    }

    // lane holds rows (w*32 + i*16 + kq*4 + r), cols (j*16 + lr)
    float cbl[16];
    const float* cbb = cb + b * 256;
#pragma unroll
    for (int j = 0; j < 16; ++j) cbl[j] = cbb[j * 16 + lr];

#pragma unroll
    for (int i = 0; i < 2; ++i)
#pragma unroll
        for (int r = 0; r < 4; ++r) {
            float m = -3.0e38f;
#pragma unroll
            for (int j = 0; j < 16; ++j) {
                float v = acc[i][j][r] + cbl[j];
                acc[i][j][r] = v;
                m = fmaxf(m, v);
            }
            m = fmaxf(m, __shfl_xor(m, 1, 64)); m = fmaxf(m, __shfl_xor(m, 2, 64));
            m = fmaxf(m, __shfl_xor(m, 4, 64)); m = fmaxf(m, __shfl_xor(m, 8, 64));
            float s = 0.f;
#pragma unroll
            for (int j = 0; j < 16; ++j) {
                float e = __expf(acc[i][j][r] - m);
                acc[i][j][r] = e;
                s += e;
            }
            s += __shfl_xor(s, 1, 64); s += __shfl_xor(s, 2, 64);
            s += __shfl_xor(s, 4, 64); s += __shfl_xor(s, 8, 64);
            const float inv = 1.0f / s;
#pragma unroll
            for (int j = 0; j < 16; ++j) acc[i][j][r] *= inv;
        }

    // pack 64-row halves through LDS (pitch 264: 16B-aligned rows, kq->bank spread)
#pragma unroll
    for (int i = 0; i < 2; ++i) {
        __syncthreads();
#pragma unroll
        for (int r = 0; r < 4; ++r)
#pragma unroll
            for (int j = 0; j < 16; ++j)
                SM[(w * 16 + kq * 4 + r) * 264 + j * 16 + lr] = (_Float16)acc[i][j][r];
        __syncthreads();
#pragma unroll
        for (int u = 0; u < 8; ++u) {
            const int idx = tid + 256 * u, row = idx >> 5, ci2 = idx & 31;
            const half8 v = *(const half8*)&SM[row * 264 + ci2 * 8];
            const long grow = (long)b * 4096 + mb * 128 + (row >> 4) * 32 + i * 16 + (row & 15);
            *(half8*)&Wts[grow * 256 + ci2 * 8] = v;
        }
    }
}

// ---------------------------------------------------------------------------
// 64x64-tile transpose+convert: src fp32 [R][C] -> dst f16 [C][R];
// optionally straight f16 copy dsth (layout of src). Batched via blockIdx.z.
// Pitch-65 LDS (2-way max aliasing, free); xh written from registers;
// half8 (16B) transposed stores.  [R5 post-mortem: memory-system-bound]
// ---------------------------------------------------------------------------
__global__ __launch_bounds__(256) void tr64(const float* __restrict__ src,
                                            _Float16* __restrict__ dst,
                                            _Float16* __restrict__ dsth,
                                            int R, int C, long sbatch, long dbatch) {
    __shared__ float T[64 * 65];
    const float* s = src + (long)blockIdx.z * sbatch;
    _Float16* d = dst + (long)blockIdx.z * dbatch;
    _Float16* dh = dsth ? dsth + (long)blockIdx.z * sbatch : nullptr;
    const int c0 = blockIdx.x * 64, r0 = blockIdx.y * 64;
    const int t = threadIdx.x;
    {
        // read: thread t covers row = t>>2, cols cp..cp+15 (64 B contiguous)
        const int row = t >> 2, cp = (t & 3) * 16;
        const float* sp = s + (long)(r0 + row) * C + c0 + cp;
        const float4 v0 = *(const float4*)(sp + 0);
        const float4 v1 = *(const float4*)(sp + 4);
        const float4 v2 = *(const float4*)(sp + 8);
        const float4 v3 = *(const float4*)(sp + 12);
        float* Tr = &T[row * 65 + cp];
        Tr[ 0] = v0.x; Tr[ 1] = v0.y; Tr[ 2] = v0.z; Tr[ 3] = v0.w;
        Tr[ 4] = v1.x; Tr[ 5] = v1.y; Tr[ 6] = v1.z; Tr[ 7] = v1.w;
        Tr[ 8] = v2.x; Tr[ 9] = v2.y; Tr[10] = v2.z; Tr[11] = v2.w;
        Tr[12] = v3.x; Tr[13] = v3.y; Tr[14] = v3.z; Tr[15] = v3.w;
        if (dh) {
            half8 h0, h1;
            h0[0] = (_Float16)v0.x; h0[1] = (_Float16)v0.y;
            h0[2] = (_Float16)v0.z; h0[3] = (_Float16)v0.w;
            h0[4] = (_Float16)v1.x; h0[5] = (_Float16)v1.y;
            h0[6] = (_Float16)v1.z; h0[7] = (_Float16)v1.w;
            h1[0] = (_Float16)v2.x; h1[1] = (_Float16)v2.y;
            h1[2] = (_Float16)v2.z; h1[3] = (_Float16)v2.w;
            h1[4] = (_Float16)v3.x; h1[5] = (_Float16)v3.y;
            h1[6] = (_Float16)v3.z; h1[7] = (_Float16)v3.w;
            _Float16* dp = dh + (long)(r0 + row) * C + c0 + cp;
            *(half8*)(dp + 0) = h0;
            *(half8*)(dp + 8) = h1;
        }
    }
    __syncthreads();
    {
        // write: thread t covers dst row (col of src) col = cc(+32), src rows qq*8..qq*8+7
        const int qq = t & 7, cc = t >> 3;
#pragma unroll
        for (int it = 0; it < 2; ++it) {
            const int col = cc + it * 32;
            half8 o;
#pragma unroll
            for (int u = 0; u < 8; ++u) o[u] = (_Float16)T[(qq * 8 + u) * 65 + col];
            *(half8*)(d + (long)(c0 + col) * R + r0 + qq * 8) = o;
        }
    }
}

// column sums of Hk and Hv (each [4096][256]) -> sk[256], sv[256]
__global__ void colsum2(const float* __restrict__ Hk, const float* __restrict__ Hv,
                        float* __restrict__ sk, float* __restrict__ sv) {
    const float* H = blockIdx.y ? Hv : Hk;
    float* s = blockIdx.y ? sv : sk;
    const int c = threadIdx.x;
    const long r0 = (long)blockIdx.x * 64;
    float acc = 0.f;
    for (int r = 0; r < 64; ++r) acc += H[(r0 + r) * 256 + c];
    atomicAdd(s + c, acc);
}

// g[c]=bq.Wk[c,:]/32 ; h[e]=bk.Wq[e,:]/32 ; gh[2048]=bq.bk/32  (one wave each)
__global__ void bias_vecs(const float* __restrict__ W, const float* __restrict__ b,
                          float* __restrict__ gh) {
    const int wid = blockIdx.x * 4 + (threadIdx.x >> 6);
    const int ln = threadIdx.x & 63;
    float acc = 0.f;
    if (wid < 1024) {
        for (int j = 0; j < 16; ++j) { int d = ln + 64 * j; acc += b[d] * W[(long)wid * 3072 + 1024 + d]; }
    } else if (wid < 2048) {
        for (int j = 0; j < 16; ++j) { int d = ln + 64 * j; acc += b[1024 + d] * W[(long)(wid - 1024) * 3072 + d]; }
    } else if (wid == 2048) {
        for (int j = 0; j < 16; ++j) { int d = ln + 64 * j; acc += b[d] * b[1024 + d]; }
    } else return;
#pragma unroll
    for (int o = 32; o > 0; o >>= 1) acc += __shfl_xor(acc, o, 64);
    if (!ln) gh[wid] = acc * 0.03125f;
}

// cb[b*256+kk] = sum_c Pk[b][kk][c]*g[c] + sk[kk]*gh[2048]   (one wave each)
// R6: Pkv layout [8 b][512 (k|v)][1024] -> k-row of (b,kk) at b*524288 + kk*1024.
__global__ void cb_kernel(const _Float16* __restrict__ Pk, const float* __restrict__ gh,
                          const float* __restrict__ sk, float* __restrict__ cb) {
    const int wid = blockIdx.x * 4 + (threadIdx.x >> 6);
    const int ln = threadIdx.x & 63;
    const _Float16* row = Pk + (long)(wid >> 8) * 524288 + (long)(wid & 255) * 1024;
    float acc = 0.f;
    for (int j = 0; j < 16; ++j) { int c = ln + 64 * j; acc += (float)row[c] * gh[c]; }
#pragma unroll
    for (int o = 32; o > 0; o >>= 1) acc += __shfl_xor(acc, o, 64);
    if (!ln) cb[wid] = acc + sk[wid & 255] * gh[2048];
}

extern "C" void kernel_launch(void* const* d_in, const int* in_sizes, int n_in,
                              void* d_out, int out_size, void* d_ws, size_t ws_size,
                              hipStream_t stream) {
    const float* x    = (const float*)d_in[0]; // [8,4096,1024]
    const float* Wq   = (const float*)d_in[1]; // [1024,3072]
    const float* bqkv = (const float*)d_in[2]; // [3072]
    const float* Hk   = (const float*)d_in[3]; // [4096,256]
    const float* Hv   = (const float*)d_in[4]; // [4096,256]
    float* out = (float*)d_out;                // [8,4096,1024]

    char* p = (char*)d_ws;
    auto take = [&](size_t n) { char* r = p; p += (n + 255) & ~(size_t)255; return r; };
    _Float16* xh  = (_Float16*)take(33554432ull * 2); // x f16 [32768,1024]
    _Float16* xt  = (_Float16*)take(33554432ull * 2); // x^T f16 [8][1024][4096]
    _Float16* Wt  = (_Float16*)take(3145728ull * 2);  // W^T f16 [3072][1024]
    _Float16* Wh  = (_Float16*)take(3145728ull * 2);  // W f16 [1024][3072]
    _Float16* Hkv = (_Float16*)take(2097152ull * 2);  // Hk^T ++ Hv^T = [512][4096]
    _Float16* Pkv = (_Float16*)take(4194304ull * 2);  // [8 b][512 (k|v)][1024 d]
    _Float16* VpT = (_Float16*)take(2097152ull * 2);  // V_proj^T [8][1024][256]
    _Float16* Gt  = (_Float16*)take(1048576ull * 2);  // [1024 d][1024 c]
    _Float16* Mt  = (_Float16*)take(2097152ull * 2);  // [8][256][1024]
    float*    gh  = (float*)take(2049 * 4);           // g[1024] ++ h[1024] ++ bq.bk/32
    float*    sk  = (float*)take(512 * 4);            // sk[256] ++ sv[256]
    float*    sv  = sk + 256;
    float*    cbv = (float*)take(2048 * 4);           // score bias per (b,kk)
    _Float16* wts = (_Float16*)take(8388608ull * 2);  // softmax weights f16

    const dim3 B256(256);

    // --- input prep ---
    tr64<<<dim3(16, 64, 8), B256, 0, stream>>>(x, xt, xh, 4096, 1024, 4194304, 4194304);
    tr64<<<dim3(48, 16, 1), B256, 0, stream>>>(Wq, Wt, Wh, 1024, 3072, 0, 0);
    tr64<<<dim3(4, 64, 1), B256, 0, stream>>>(Hk, Hkv, nullptr, 4096, 256, 0, 0);
    tr64<<<dim3(4, 64, 1), B256, 0, stream>>>(Hv, Hkv + 1048576, nullptr, 4096, 256, 0, 0);
    hipMemsetAsync(sk, 0, 512 * 4, stream);
    colsum2<<<dim3(64, 2, 1), B256, 0, stream>>>(Hk, Hv, sk, sv);
    bias_vecs<<<513, B256, 0, stream>>>(Wq, bqkv, gh);

    // --- Gt[d][c] = sum_e W[d][e]*W[c][1024+e] : K=1024 ---
    gemm_bt<_Float16, true><<<dim3(64, 1, 1), B256, 0, stream>>>(
        Wh, 0, 0, 0, 3072, Wh + 1024, 0, 0, 0, 3072, Gt, 0, 0, 0, 1024,
        1, 1, 8, 8, 1024, nullptr, 0, nullptr, nullptr, 1.0f);
    // --- Pkv[b] = Hkv x[b]: kv merged into M (512 rows), single-pass K=4096,
    //     fp32 reg accumulation, direct f16 output (R6: no fp32 round-trip) ---
    gemm_bt<_Float16, false><<<dim3(32, 1, 8), B256, 0, stream>>>(
        Hkv, 0, 0, 0, 4096, xt, 4194304, 0, 0, 4096,
        Pkv, 524288, 0, 0, 1024,
        8, 1, 4, 8, 4096, nullptr, 0, nullptr, nullptr, 1.0f);
    // --- V_proj^T = Wv^T Pv^T + bv (x) sv : [8][1024][256], K=1024 ---
    gemm_bt<_Float16, true><<<dim3(16, 1, 8), B256, 0, stream>>>(
        Wt + 2097152, 0, 0, 0, 1024, Pkv + 262144, 524288, 0, 0, 1024,
        VpT, 262144, 0, 0, 256,
        8, 1, 8, 2, 1024, nullptr, 0, bqkv + 2048, sv, 1.0f);
    // --- Mt = Pk*Gt^T/32 + sk (x) h : [8][256][1024], K=1024 ---
    gemm_bt<_Float16, false><<<dim3(16, 1, 8), B256, 0, stream>>>(
        Pkv, 524288, 0, 0, 1024, Gt, 0, 0, 0, 1024,
        Mt, 262144, 0, 0, 1024,
        8, 1, 2, 8, 1024, nullptr, 0, sk, gh + 1024, 0.03125f);
    // --- cb[b][kk] = Pk.g + sk*(bq.bk)  (already /32) ---
    cb_kernel<<<512, B256, 0, stream>>>(Pkv, gh, sk, cbv);
    // --- fused scores+softmax -> wts f16 [8][4096][256] ---
    score_softmax<<<dim3(32, 1, 8), B256, 0, stream>>>(xh, Mt, cbv, wts);
    // --- out = weights V_proj : fp32 [8][4096][1024], K=256 (NT stores) ---
    gemm_bt<float, true><<<dim3(256, 1, 8), B256, 0, stream>>>(
        wts, 1048576, 0, 0, 256, VpT, 262144, 0, 0, 256,
        out, 4194304, 0, 0, 1024,
        8, 1, 32, 8, 256, nullptr, 0, nullptr, nullptr, 1.0f);
}

// Round 6
// 492.450 us; speedup vs baseline: 1.0776x; 1.0776x over previous
//
#include <hip/hip_runtime.h>

// ---------------------------------------------------------------------------
// Linformer self-attention, MI355X (gfx950).  Round 9 = R5 (verified 509.7us)
//   + (a) xh deleted: score_softmax reads x fp32 with reg-staged f16 convert
//   + (b) out-GEMM nontemporal stores (verified in R6).
//   R7/R8 post-mortem: bit-identical failures across a real operand swap —
//   unresolvable blind; retreating to verified trunk, bisecting one delta at
//   a time. R9 isolates the fp32-reg-staging path on top of verified math.
//   Gt = Wq*Wk^T;  Mt[b] = Pk[b]*Gt^T/32 + sk(x)h;  scores = x*Mt^T + cb[b]
// Generic gemm_bt: 128x128 tile, BK=64, global_load_lds width-16,
// ds_read_b128 frags, XCD panel swizzle, XOR bank swizzle (0 conflicts, R2).
// fp16 (not bf16): softmax is near-argmax; bf16 score noise fails threshold.
// ---------------------------------------------------------------------------

typedef __attribute__((ext_vector_type(8))) _Float16 half8;
typedef __attribute__((ext_vector_type(4))) _Float16 half4;
typedef __attribute__((ext_vector_type(4))) float f32x4;

#define AS1 __attribute__((address_space(1)))
#define AS3 __attribute__((address_space(3)))

__device__ __forceinline__ void gld_lds16(const void* g, void* l) {
    __builtin_amdgcn_global_load_lds((AS1 void*)g, (AS3 void*)l, 16, 0, 0);
}

template <typename T> struct is_f32 { static constexpr bool v = false; };
template <> struct is_f32<float> { static constexpr bool v = true; };

template <typename T> __device__ __forceinline__ T to_out(float v);
template <> __device__ __forceinline__ float    to_out<float>(float v) { return v; }
template <> __device__ __forceinline__ _Float16 to_out<_Float16>(float v) { return (_Float16)v; }

__device__ __forceinline__ half8 cvt_h8(f32x4 a, f32x4 b) {
    half8 h;
    h[0] = (_Float16)a[0]; h[1] = (_Float16)a[1]; h[2] = (_Float16)a[2]; h[3] = (_Float16)a[3];
    h[4] = (_Float16)b[0]; h[5] = (_Float16)b[1]; h[6] = (_Float16)b[2]; h[7] = (_Float16)b[3];
    return h;
}

// ---------------------------------------------------------------------------
// C[m,n] = scale * sum_k A[m,k]*B[n,k] (+bias[n], batched by sb0) (+rowv[m]*colv[n])
// float outputs use nontemporal stores (only the final `out` GEMM emits fp32).
// ---------------------------------------------------------------------------
template <typename OUT_T, bool SWIZ>
__global__ __launch_bounds__(256) void gemm_bt(
    const _Float16* __restrict__ A, long sA0, long sA1, long sA2, int lda,
    const _Float16* __restrict__ B, long sB0, long sB1, long sB2, int ldb,
    OUT_T* __restrict__ C, long sC0, long sC1, long sC2, int ldc,
    int nz0, int nz1, int NM, int NN, int Kd,
    const float* __restrict__ bias, long sb0,
    const float* __restrict__ rowv, const float* __restrict__ colv, float scale)
{
    {   // z-decode: 3-level batching
        const int z = blockIdx.z;
        const int z0 = z % nz0, t = z / nz0, z1 = t % nz1, z2 = t / nz1;
        A += z0 * sA0 + z1 * sA1 + z2 * sA2;
        B += z0 * sB0 + z1 * sB1 + z2 * sB2;
        C += z0 * sC0 + z1 * sC1 + z2 * sC2;
        if (bias) bias += (long)z0 * sb0;
    }
    int mb, nb;
    if (SWIZ) {  // requires NM % 8 == 0: XCD keeps one A-panel hot
        const int g = blockIdx.x, r = g % (8 * NN);
        mb = (g / (8 * NN)) * 8 + (r & 7);
        nb = r >> 3;
    } else {
        mb = blockIdx.x % NM;
        nb = blockIdx.x / NM;
    }
    const int tid = threadIdx.x, w = tid >> 6, ln = tid & 63;
    const int wm = (w >> 1) * 64, wn = (w & 1) * 64;

    __shared__ __attribute__((aligned(16))) _Float16 As[128 * 64];
    __shared__ __attribute__((aligned(16))) _Float16 Bs[128 * 64];

    f32x4 acc[4][4] = {};

    const int cb0 = w * 256;
    const _Float16* Ablk = A + (long)mb * 128 * lda;
    const _Float16* Bblk = B + (long)nb * 128 * ldb;

    const int lr = ln & 15, rs = ln & 7, kq = ln >> 4;

    for (int k0 = 0; k0 < Kd; k0 += 64) {
#pragma unroll
        for (int t = 0; t < 4; ++t) {
            const int ci = cb0 + t * 64 + ln;
            const int r = ci >> 3, kc = (ci & 7) ^ (r & 7);
            gld_lds16(Ablk + (long)r * lda + k0 + kc * 8, &As[(cb0 + t * 64) * 8]);
            gld_lds16(Bblk + (long)r * ldb + k0 + kc * 8, &Bs[(cb0 + t * 64) * 8]);
        }
        __syncthreads();
#pragma unroll
        for (int kh = 0; kh < 2; ++kh) {
            const int c = (((kh * 4) + kq) ^ rs) * 8;
            half8 af[4], bf[4];
#pragma unroll
            for (int i = 0; i < 4; ++i) {
                af[i] = *(const half8*)&As[(wm + i * 16 + lr) * 64 + c];
                bf[i] = *(const half8*)&Bs[(wn + i * 16 + lr) * 64 + c];
            }
#pragma unroll
            for (int i = 0; i < 4; ++i)
#pragma unroll
                for (int j = 0; j < 4; ++j)
                    acc[i][j] = __builtin_amdgcn_mfma_f32_16x16x32_f16(af[i], bf[j], acc[i][j], 0, 0, 0);
        }
        __syncthreads();
    }

    // C/D layout: col = lane&15, row = (lane>>4)*4 + reg
    const int crow = mb * 128 + wm + (kq << 2);
    const int ccol = nb * 128 + wn + lr;
#pragma unroll
    for (int i = 0; i < 4; ++i)
#pragma unroll
        for (int r = 0; r < 4; ++r) {
            const long row = crow + i * 16 + r;
#pragma unroll
            for (int j = 0; j < 4; ++j) {
                const int col = ccol + j * 16;
                float v = acc[i][j][r] * scale;
                if (bias) v += bias[col];
                if (rowv) v += rowv[row] * colv[col];
                if constexpr (is_f32<OUT_T>::v)
                    __builtin_nontemporal_store(v, &C[row * ldc + col]);
                else
                    C[row * ldc + col] = to_out<OUT_T>(v);
            }
        }
}

// ---------------------------------------------------------------------------
// Fused scores+softmax: wts[b][l][kk] = softmax_kk( x[b][l]:Mt[b][kk] + cb[b][kk] )
// Block = 128 rows x 256 cols. A = x fp32 (reg-staged f16 convert, R9);
// B = Mt f16 via global_load_lds.
// ---------------------------------------------------------------------------
__global__ __launch_bounds__(256) void score_softmax(
    const float* __restrict__ X, const _Float16* __restrict__ Bm,
    const float* __restrict__ cb, _Float16* __restrict__ Wts)
{
    const int b = blockIdx.z, mb = blockIdx.x;
    const float* Ab = X + (long)b * 4194304 + (long)mb * 131072;
    const _Float16* Bb = Bm + (long)b * 262144;
    const int tid = threadIdx.x, w = tid >> 6, ln = tid & 63;
    const int lr = ln & 15, rs = ln & 7, kq = ln >> 4;

    __shared__ __attribute__((aligned(16))) _Float16 SM[24576]; // As 8192 | Bs 16384
    _Float16* As = SM;
    _Float16* Bs = SM + 8192;

    f32x4 acc[2][16] = {};

    for (int k0 = 0; k0 < 1024; k0 += 64) {
        f32x4 pa[4][2];
#pragma unroll
        for (int t = 0; t < 4; ++t) {           // A-tile loads: 128x64 fp32
            const int ci = w * 256 + t * 64 + ln;
            const int r = ci >> 3, kc = (ci & 7) ^ (r & 7);
            const float* ap = Ab + (long)r * 1024 + k0 + kc * 8;
            pa[t][0] = *(const f32x4*)ap;
            pa[t][1] = *(const f32x4*)(ap + 4);
        }
#pragma unroll
        for (int t = 0; t < 8; ++t) {           // B-tile: 256x64 f16 via gld_lds
            const int cbase = w * 512 + t * 64;
            const int ci = cbase + ln, r = ci >> 3, kc = (ci & 7) ^ (r & 7);
            gld_lds16(Bb + (long)r * 1024 + k0 + kc * 8, &Bs[cbase * 8]);
        }
#pragma unroll
        for (int t = 0; t < 4; ++t) {           // A-tile writes (cvt f16)
            const int ci = w * 256 + t * 64 + ln;
            *(half8*)&As[ci * 8] = cvt_h8(pa[t][0], pa[t][1]);
        }
        __syncthreads();
#pragma unroll
        for (int kh = 0; kh < 2; ++kh) {
            const int c = (((kh * 4) + kq) ^ rs) * 8;
            const half8 af0 = *(const half8*)&As[(w * 32 + lr) * 64 + c];
            const half8 af1 = *(const half8*)&As[(w * 32 + 16 + lr) * 64 + c];
#pragma unroll
            for (int j = 0; j < 16; ++j) {
                const half8 bf = *(const half8*)&Bs[(j * 16 + lr) * 64 + c];
                acc[0][j] = __builtin_amdgcn_mfma_f32_16x16x32_f16(af0, bf, acc[0][j], 0, 0, 0);
                acc[1][j] = __builtin_amdgcn_mfma_f32_16x16x32_f16(af1, bf, acc[1][j], 0, 0, 0);
            }
        }
        __syncthreads();
    }

    // lane holds rows (w*32 + i*16 + kq*4 + r), cols (j*16 + lr)
    float cbl[16];
    const float* cbb = cb + b * 256;
#pragma unroll
    for (int j = 0; j < 16; ++j) cbl[j] = cbb[j * 16 + lr];

#pragma unroll
    for (int i = 0; i < 2; ++i)
#pragma unroll
        for (int r = 0; r < 4; ++r) {
            float m = -3.0e38f;
#pragma unroll
            for (int j = 0; j < 16; ++j) {
                float v = acc[i][j][r] + cbl[j];
                acc[i][j][r] = v;
                m = fmaxf(m, v);
            }
            m = fmaxf(m, __shfl_xor(m, 1, 64)); m = fmaxf(m, __shfl_xor(m, 2, 64));
            m = fmaxf(m, __shfl_xor(m, 4, 64)); m = fmaxf(m, __shfl_xor(m, 8, 64));
            float s = 0.f;
#pragma unroll
            for (int j = 0; j < 16; ++j) {
                float e = __expf(acc[i][j][r] - m);
                acc[i][j][r] = e;
                s += e;
            }
            s += __shfl_xor(s, 1, 64); s += __shfl_xor(s, 2, 64);
            s += __shfl_xor(s, 4, 64); s += __shfl_xor(s, 8, 64);
            const float inv = 1.0f / s;
#pragma unroll
            for (int j = 0; j < 16; ++j) acc[i][j][r] *= inv;
        }

    // pack 64-row halves through LDS (pitch 264: 16B-aligned rows, kq->bank spread)
#pragma unroll
    for (int i = 0; i < 2; ++i) {
        __syncthreads();
#pragma unroll
        for (int r = 0; r < 4; ++r)
#pragma unroll
            for (int j = 0; j < 16; ++j)
                SM[(w * 16 + kq * 4 + r) * 264 + j * 16 + lr] = (_Float16)acc[i][j][r];
        __syncthreads();
#pragma unroll
        for (int u = 0; u < 8; ++u) {
            const int idx = tid + 256 * u, row = idx >> 5, ci2 = idx & 31;
            const half8 v = *(const half8*)&SM[row * 264 + ci2 * 8];
            const long grow = (long)b * 4096 + mb * 128 + (row >> 4) * 32 + i * 16 + (row & 15);
            *(half8*)&Wts[grow * 256 + ci2 * 8] = v;
        }
    }
}

// ---------------------------------------------------------------------------
// 64x64-tile transpose+convert: src fp32 [R][C] -> dst f16 [C][R];
// optionally straight f16 copy dsth (layout of src). Batched via blockIdx.z.
// Pitch-65 LDS (2-way max aliasing, free); half8 (16B) transposed stores.
// ---------------------------------------------------------------------------
__global__ __launch_bounds__(256) void tr64(const float* __restrict__ src,
                                            _Float16* __restrict__ dst,
                                            _Float16* __restrict__ dsth,
                                            int R, int C, long sbatch, long dbatch) {
    __shared__ float T[64 * 65];
    const float* s = src + (long)blockIdx.z * sbatch;
    _Float16* d = dst + (long)blockIdx.z * dbatch;
    _Float16* dh = dsth ? dsth + (long)blockIdx.z * sbatch : nullptr;
    const int c0 = blockIdx.x * 64, r0 = blockIdx.y * 64;
    const int t = threadIdx.x;
    {
        // read: thread t covers row = t>>2, cols cp..cp+15 (64 B contiguous)
        const int row = t >> 2, cp = (t & 3) * 16;
        const float* sp = s + (long)(r0 + row) * C + c0 + cp;
        const float4 v0 = *(const float4*)(sp + 0);
        const float4 v1 = *(const float4*)(sp + 4);
        const float4 v2 = *(const float4*)(sp + 8);
        const float4 v3 = *(const float4*)(sp + 12);
        float* Tr = &T[row * 65 + cp];
        Tr[ 0] = v0.x; Tr[ 1] = v0.y; Tr[ 2] = v0.z; Tr[ 3] = v0.w;
        Tr[ 4] = v1.x; Tr[ 5] = v1.y; Tr[ 6] = v1.z; Tr[ 7] = v1.w;
        Tr[ 8] = v2.x; Tr[ 9] = v2.y; Tr[10] = v2.z; Tr[11] = v2.w;
        Tr[12] = v3.x; Tr[13] = v3.y; Tr[14] = v3.z; Tr[15] = v3.w;
        if (dh) {
            half8 h0, h1;
            h0[0] = (_Float16)v0.x; h0[1] = (_Float16)v0.y;
            h0[2] = (_Float16)v0.z; h0[3] = (_Float16)v0.w;
            h0[4] = (_Float16)v1.x; h0[5] = (_Float16)v1.y;
            h0[6] = (_Float16)v1.z; h0[7] = (_Float16)v1.w;
            h1[0] = (_Float16)v2.x; h1[1] = (_Float16)v2.y;
            h1[2] = (_Float16)v2.z; h1[3] = (_Float16)v2.w;
            h1[4] = (_Float16)v3.x; h1[5] = (_Float16)v3.y;
            h1[6] = (_Float16)v3.z; h1[7] = (_Float16)v3.w;
            _Float16* dp = dh + (long)(r0 + row) * C + c0 + cp;
            *(half8*)(dp + 0) = h0;
            *(half8*)(dp + 8) = h1;
        }
    }
    __syncthreads();
    {
        // write: thread t covers dst row (col of src) col = cc(+32), src rows qq*8..qq*8+7
        const int qq = t & 7, cc = t >> 3;
#pragma unroll
        for (int it = 0; it < 2; ++it) {
            const int col = cc + it * 32;
            half8 o;
#pragma unroll
            for (int u = 0; u < 8; ++u) o[u] = (_Float16)T[(qq * 8 + u) * 65 + col];
            *(half8*)(d + (long)(c0 + col) * R + r0 + qq * 8) = o;
        }
    }
}

// column sums of Hk and Hv (each [4096][256]) -> sk[256], sv[256]
__global__ void colsum2(const float* __restrict__ Hk, const float* __restrict__ Hv,
                        float* __restrict__ sk, float* __restrict__ sv) {
    const float* H = blockIdx.y ? Hv : Hk;
    float* s = blockIdx.y ? sv : sk;
    const int c = threadIdx.x;
    const long r0 = (long)blockIdx.x * 64;
    float acc = 0.f;
    for (int r = 0; r < 64; ++r) acc += H[(r0 + r) * 256 + c];
    atomicAdd(s + c, acc);
}

// g[c]=bq.Wk[c,:]/32 ; h[e]=bk.Wq[e,:]/32 ; gh[2048]=bq.bk/32  (one wave each)
__global__ void bias_vecs(const float* __restrict__ W, const float* __restrict__ b,
                          float* __restrict__ gh) {
    const int wid = blockIdx.x * 4 + (threadIdx.x >> 6);
    const int ln = threadIdx.x & 63;
    float acc = 0.f;
    if (wid < 1024) {
        for (int j = 0; j < 16; ++j) { int d = ln + 64 * j; acc += b[d] * W[(long)wid * 3072 + 1024 + d]; }
    } else if (wid < 2048) {
        for (int j = 0; j < 16; ++j) { int d = ln + 64 * j; acc += b[1024 + d] * W[(long)(wid - 1024) * 3072 + d]; }
    } else if (wid == 2048) {
        for (int j = 0; j < 16; ++j) { int d = ln + 64 * j; acc += b[d] * b[1024 + d]; }
    } else return;
#pragma unroll
    for (int o = 32; o > 0; o >>= 1) acc += __shfl_xor(acc, o, 64);
    if (!ln) gh[wid] = acc * 0.03125f;
}

// cb[b*256+kk] = sum_c Pk[b][kk][c]*g[c] + sk[kk]*gh[2048]   (one wave each)
__global__ void cb_kernel(const _Float16* __restrict__ Pk, const float* __restrict__ gh,
                          const float* __restrict__ sk, float* __restrict__ cb) {
    const int wid = blockIdx.x * 4 + (threadIdx.x >> 6);
    const int ln = threadIdx.x & 63;
    const _Float16* row = Pk + (long)wid * 1024;
    float acc = 0.f;
    for (int j = 0; j < 16; ++j) { int c = ln + 64 * j; acc += (float)row[c] * gh[c]; }
#pragma unroll
    for (int o = 32; o > 0; o >>= 1) acc += __shfl_xor(acc, o, 64);
    if (!ln) cb[wid] = acc + sk[wid & 255] * gh[2048];
}

// Pkv[kv][b][kk][d] = f16( P32[0][b][kv*256+kk][d] + P32[1][b][kv*256+kk][d] )
__global__ void reduce_kv(const float* __restrict__ P, _Float16* __restrict__ Pkv) {
    const long o = ((long)blockIdx.x * 256 + threadIdx.x) * 4;
    const int kv = (int)(o >> 21), b = (int)(o >> 18) & 7;
    const long r = o & 262143;
    const long i = (long)b * 524288 + (long)kv * 262144 + r;
    float4 a = *(const float4*)(P + i);
    float4 bb = *(const float4*)(P + i + 4194304);
    half4 out;
    out[0] = (_Float16)(a.x + bb.x); out[1] = (_Float16)(a.y + bb.y);
    out[2] = (_Float16)(a.z + bb.z); out[3] = (_Float16)(a.w + bb.w);
    *(half4*)(Pkv + o) = out;
}

extern "C" void kernel_launch(void* const* d_in, const int* in_sizes, int n_in,
                              void* d_out, int out_size, void* d_ws, size_t ws_size,
                              hipStream_t stream) {
    const float* x    = (const float*)d_in[0]; // [8,4096,1024]
    const float* Wq   = (const float*)d_in[1]; // [1024,3072]
    const float* bqkv = (const float*)d_in[2]; // [3072]
    const float* Hk   = (const float*)d_in[3]; // [4096,256]
    const float* Hv   = (const float*)d_in[4]; // [4096,256]
    float* out = (float*)d_out;                // [8,4096,1024]

    char* p = (char*)d_ws;
    auto take = [&](size_t n) { char* r = p; p += (n + 255) & ~(size_t)255; return r; };
    _Float16* xt  = (_Float16*)take(33554432ull * 2); // x^T f16 [8][1024][4096]
    _Float16* Wt  = (_Float16*)take(3145728ull * 2);  // W^T f16 [3072][1024]
    _Float16* Wh  = (_Float16*)take(3145728ull * 2);  // W f16 [1024][3072]
    _Float16* Hkv = (_Float16*)take(2097152ull * 2);  // Hk^T ++ Hv^T = [512][4096]
    _Float16* Pkv = (_Float16*)take(4194304ull * 2);  // [2(kv)][8][256][1024]
    _Float16* VpT = (_Float16*)take(2097152ull * 2);  // V_proj^T [8][1024][256]
    _Float16* Gt  = (_Float16*)take(1048576ull * 2);  // [1024 d][1024 c]
    _Float16* Mt  = (_Float16*)take(2097152ull * 2);  // [8][256][1024]
    float*    gh  = (float*)take(2049 * 4);           // g[1024] ++ h[1024] ++ bq.bk/32
    float*    sk  = (float*)take(512 * 4);            // sk[256] ++ sv[256]
    float*    sv  = sk + 256;
    float*    cbv = (float*)take(2048 * 4);           // score bias per (b,kk)
    float*    P32 = (float*)take(8388608ull * 4);     // [2ks][8b][512][1024]
    _Float16* wts = (_Float16*)take(8388608ull * 2);  // softmax weights f16

    const dim3 B256(256);

    // --- input prep (R9: no xh — score reads x fp32 directly) ---
    tr64<<<dim3(16, 64, 8), B256, 0, stream>>>(x, xt, nullptr, 4096, 1024, 4194304, 4194304);
    tr64<<<dim3(48, 16, 1), B256, 0, stream>>>(Wq, Wt, Wh, 1024, 3072, 0, 0);
    tr64<<<dim3(4, 64, 1), B256, 0, stream>>>(Hk, Hkv, nullptr, 4096, 256, 0, 0);
    tr64<<<dim3(4, 64, 1), B256, 0, stream>>>(Hv, Hkv + 1048576, nullptr, 4096, 256, 0, 0);
    hipMemsetAsync(sk, 0, 512 * 4, stream);
    colsum2<<<dim3(64, 2, 1), B256, 0, stream>>>(Hk, Hv, sk, sv);
    bias_vecs<<<513, B256, 0, stream>>>(Wq, bqkv, gh);

    // --- Gt[d][c] = sum_e W[d][e]*W[c][1024+e] : K=1024 ---
    gemm_bt<_Float16, true><<<dim3(64, 1, 1), B256, 0, stream>>>(
        Wh, 0, 0, 0, 3072, Wh + 1024, 0, 0, 0, 3072, Gt, 0, 0, 0, 1024,
        1, 1, 8, 8, 1024, nullptr, 0, nullptr, nullptr, 1.0f);
    // --- P32 = Hkv^T-stacked x, kv merged into M (512 rows), K-split 2x2048:
    //     z = b + 8*ks (16 z-blocks x 32 mn-blocks) ---
    gemm_bt<float, false><<<dim3(32, 1, 16), B256, 0, stream>>>(
        Hkv, 0, 2048, 0, 4096, xt, 4194304, 2048, 0, 4096,
        P32, 524288, 4194304, 0, 1024,
        8, 2, 4, 8, 2048, nullptr, 0, nullptr, nullptr, 1.0f);
    reduce_kv<<<4096, B256, 0, stream>>>(P32, Pkv);
    // --- V_proj^T = Wv^T Pv^T + bv (x) sv : [8][1024][256], K=1024 ---
    gemm_bt<_Float16, true><<<dim3(16, 1, 8), B256, 0, stream>>>(
        Wt + 2097152, 0, 0, 0, 1024, Pkv + 2097152, 262144, 0, 0, 1024,
        VpT, 262144, 0, 0, 256,
        8, 1, 8, 2, 1024, nullptr, 0, bqkv + 2048, sv, 1.0f);
    // --- Mt = Pk*Gt^T/32 + sk (x) h : [8][256][1024], K=1024 ---
    gemm_bt<_Float16, false><<<dim3(16, 1, 8), B256, 0, stream>>>(
        Pkv, 262144, 0, 0, 1024, Gt, 0, 0, 0, 1024,
        Mt, 262144, 0, 0, 1024,
        8, 1, 2, 8, 1024, nullptr, 0, sk, gh + 1024, 0.03125f);
    // --- cb[b][kk] = Pk.g + sk*(bq.bk)  (already /32) ---
    cb_kernel<<<512, B256, 0, stream>>>(Pkv, gh, sk, cbv);
    // --- fused scores+softmax -> wts f16 [8][4096][256] (A = x fp32, R9) ---
    score_softmax<<<dim3(32, 1, 8), B256, 0, stream>>>(x, Mt, cbv, wts);
    // --- out = weights V_proj : fp32 [8][4096][1024], K=256 (NT stores) ---
    gemm_bt<float, true><<<dim3(256, 1, 8), B256, 0, stream>>>(
        wts, 1048576, 0, 0, 256, VpT, 262144, 0, 0, 256,
        out, 4194304, 0, 0, 1024,
        8, 1, 32, 8, 256, nullptr, 0, nullptr, nullptr, 1.0f);
}

// Round 10
// 468.246 us; speedup vs baseline: 1.1333x; 1.0517x over previous
//
#include <hip/hip_runtime.h>

// ---------------------------------------------------------------------------
// Linformer self-attention, MI355X (gfx950).  Round 10 (3rd resubmit — three
// consecutive GPUAcquisitionTimeouts; experiment has never executed).
//   = R9 (verified 492.5us)
//   + ONE new kernel under test: gemm_tn_pkv — tn-orientation PkvT GEMM
//     reading x/Hk/Hv NATIVELY (fp32), reg-staged transpose+cvt to LDS,
//     2-phase pipeline, K-split 2x2048, TRANSPOSED f32x4 store producing
//     P32 in R6's verified [ks][b][512 kk][1024 e] layout.
//   DELETED: tr64-x (62us), tr64-Hk, tr64-Hv, xt (128 MB traffic), Hkv.
//   Downstream (reduce_kv2, VpT, Mt, cb_kernel) = R6-verified forms.
//   Bisection note: if this fails with absmax~213, gemm_tn staging is the
//   R7/R8 culprit (score's fp32 staging + NT stores verified in R9).
//   Gt = Wq*Wk^T;  Mt[b] = Pk[b]*Gt^T/32 + sk(x)h;  scores = x*Mt^T + cb[b]
// fp16 (not bf16): softmax is near-argmax; bf16 score noise fails threshold.
// ---------------------------------------------------------------------------

typedef __attribute__((ext_vector_type(8))) _Float16 half8;
typedef __attribute__((ext_vector_type(4))) _Float16 half4;
typedef __attribute__((ext_vector_type(4))) float f32x4;

#define AS1 __attribute__((address_space(1)))
#define AS3 __attribute__((address_space(3)))

__device__ __forceinline__ void gld_lds16(const void* g, void* l) {
    __builtin_amdgcn_global_load_lds((AS1 void*)g, (AS3 void*)l, 16, 0, 0);
}

template <typename T> struct is_f32 { static constexpr bool v = false; };
template <> struct is_f32<float> { static constexpr bool v = true; };

template <typename T> __device__ __forceinline__ T to_out(float v);
template <> __device__ __forceinline__ float    to_out<float>(float v) { return v; }
template <> __device__ __forceinline__ _Float16 to_out<_Float16>(float v) { return (_Float16)v; }

__device__ __forceinline__ half8 cvt_h8(f32x4 a, f32x4 b) {
    half8 h;
    h[0] = (_Float16)a[0]; h[1] = (_Float16)a[1]; h[2] = (_Float16)a[2]; h[3] = (_Float16)a[3];
    h[4] = (_Float16)b[0]; h[5] = (_Float16)b[1]; h[6] = (_Float16)b[2]; h[7] = (_Float16)b[3];
    return h;
}

// ---------------------------------------------------------------------------
// C[m,n] = scale * sum_k A[m,k]*B[n,k] (+bias[n], batched by sb0) (+rowv[m]*colv[n])
// float outputs use nontemporal stores (only the final `out` GEMM emits fp32).
// ---------------------------------------------------------------------------
template <typename OUT_T, bool SWIZ>
__global__ __launch_bounds__(256) void gemm_bt(
    const _Float16* __restrict__ A, long sA0, long sA1, long sA2, int lda,
    const _Float16* __restrict__ B, long sB0, long sB1, long sB2, int ldb,
    OUT_T* __restrict__ C, long sC0, long sC1, long sC2, int ldc,
    int nz0, int nz1, int NM, int NN, int Kd,
    const float* __restrict__ bias, long sb0,
    const float* __restrict__ rowv, const float* __restrict__ colv, float scale)
{
    {   // z-decode: 3-level batching
        const int z = blockIdx.z;
        const int z0 = z % nz0, t = z / nz0, z1 = t % nz1, z2 = t / nz1;
        A += z0 * sA0 + z1 * sA1 + z2 * sA2;
        B += z0 * sB0 + z1 * sB1 + z2 * sB2;
        C += z0 * sC0 + z1 * sC1 + z2 * sC2;
        if (bias) bias += (long)z0 * sb0;
    }
    int mb, nb;
    if (SWIZ) {  // requires NM % 8 == 0: XCD keeps one A-panel hot
        const int g = blockIdx.x, r = g % (8 * NN);
        mb = (g / (8 * NN)) * 8 + (r & 7);
        nb = r >> 3;
    } else {
        mb = blockIdx.x % NM;
        nb = blockIdx.x / NM;
    }
    const int tid = threadIdx.x, w = tid >> 6, ln = tid & 63;
    const int wm = (w >> 1) * 64, wn = (w & 1) * 64;

    __shared__ __attribute__((aligned(16))) _Float16 As[128 * 64];
    __shared__ __attribute__((aligned(16))) _Float16 Bs[128 * 64];

    f32x4 acc[4][4] = {};

    const int cb0 = w * 256;
    const _Float16* Ablk = A + (long)mb * 128 * lda;
    const _Float16* Bblk = B + (long)nb * 128 * ldb;

    const int lr = ln & 15, rs = ln & 7, kq = ln >> 4;

    for (int k0 = 0; k0 < Kd; k0 += 64) {
#pragma unroll
        for (int t = 0; t < 4; ++t) {
            const int ci = cb0 + t * 64 + ln;
            const int r = ci >> 3, kc = (ci & 7) ^ (r & 7);
            gld_lds16(Ablk + (long)r * lda + k0 + kc * 8, &As[(cb0 + t * 64) * 8]);
            gld_lds16(Bblk + (long)r * ldb + k0 + kc * 8, &Bs[(cb0 + t * 64) * 8]);
        }
        __syncthreads();
#pragma unroll
        for (int kh = 0; kh < 2; ++kh) {
            const int c = (((kh * 4) + kq) ^ rs) * 8;
            half8 af[4], bf[4];
#pragma unroll
            for (int i = 0; i < 4; ++i) {
                af[i] = *(const half8*)&As[(wm + i * 16 + lr) * 64 + c];
                bf[i] = *(const half8*)&Bs[(wn + i * 16 + lr) * 64 + c];
            }
#pragma unroll
            for (int i = 0; i < 4; ++i)
#pragma unroll
                for (int j = 0; j < 4; ++j)
                    acc[i][j] = __builtin_amdgcn_mfma_f32_16x16x32_f16(af[i], bf[j], acc[i][j], 0, 0, 0);
        }
        __syncthreads();
    }

    // C/D layout: col = lane&15, row = (lane>>4)*4 + reg
    const int crow = mb * 128 + wm + (kq << 2);
    const int ccol = nb * 128 + wn + lr;
#pragma unroll
    for (int i = 0; i < 4; ++i)
#pragma unroll
        for (int r = 0; r < 4; ++r) {
            const long row = crow + i * 16 + r;
#pragma unroll
            for (int j = 0; j < 4; ++j) {
                const int col = ccol + j * 16;
                float v = acc[i][j][r] * scale;
                if (bias) v += bias[col];
                if (rowv) v += rowv[row] * colv[col];
                if constexpr (is_f32<OUT_T>::v)
                    __builtin_nontemporal_store(v, &C[row * ldc + col]);
                else
                    C[row * ldc + col] = to_out<OUT_T>(v);
            }
        }
}

// ---------------------------------------------------------------------------
// gemm_tn_pkv (UNDER TEST): P32[ks][b][kk][e] = sum_l x[b][l,e]*H[l,kk]
// tn orientation, all operands native fp32. Reg-staged transpose+cvt to LDS
// (chunk kc stored at slot kc^(row&7) — same swizzle the verified bt read
// expects). 2-phase pipeline. TRANSPOSED f32x4 epilogue (lane stores 4
// consecutive e for fixed kk). K-split 2x2048 via z = b + 8*ks; grid 512
// blocks = 2/CU.
// ---------------------------------------------------------------------------
__global__ __launch_bounds__(256) void gemm_tn_pkv(
    const float* __restrict__ X, const float* __restrict__ Hk,
    const float* __restrict__ Hv, float* __restrict__ P32)
{
    const int z = blockIdx.z, b = z & 7, ks = z >> 3;
    const int mb = blockIdx.x & 7, nb = blockIdx.x >> 3;   // e-block, kk-block
    const float* Ab = X + (long)b * 4194304 + (long)ks * 2097152 + mb * 128;
    const float* Bb = (nb >= 2 ? Hv + (nb - 2) * 128 : Hk + nb * 128) + (long)ks * 524288;
    float* Cb = P32 + (long)ks * 4194304 + (long)b * 524288;

    const int tid = threadIdx.x, w = tid >> 6, ln = tid & 63;
    const int wm = (w >> 1) * 64, wn = (w & 1) * 64;
    const int lr = ln & 15, rs = ln & 7, kq = ln >> 4;
    const int skq = (tid >> 2) & 7;                         // staging k-chunk
    const int sm0 = ((tid & 3) | ((tid >> 5) << 2)) * 4;    // staging m base

    __shared__ __attribute__((aligned(16))) _Float16 As[128 * 64];
    __shared__ __attribute__((aligned(16))) _Float16 Bs[128 * 64];

    f32x4 acc[4][4] = {};
    f32x4 va[8], vb[8];

    // prologue: tile 0 loads (8 k-rows x 4 m-cols each operand)
#pragma unroll
    for (int i = 0; i < 8; ++i)
        va[i] = *(const f32x4*)(Ab + (long)(skq * 8 + i) * 1024 + sm0);
#pragma unroll
    for (int i = 0; i < 8; ++i)
        vb[i] = *(const f32x4*)(Bb + (long)(skq * 8 + i) * 256 + sm0);

    for (int k0 = 0; k0 < 2048; k0 += 64) {
        // regs -> LDS: in-reg transpose + f16 cvt; chunk skq at slot skq^(row&7)
#pragma unroll
        for (int j = 0; j < 4; ++j) {
            half8 h;
#pragma unroll
            for (int i = 0; i < 8; ++i) h[i] = (_Float16)va[i][j];
            *(half8*)&As[(sm0 + j) * 64 + ((skq ^ ((sm0 + j) & 7)) << 3)] = h;
        }
#pragma unroll
        for (int j = 0; j < 4; ++j) {
            half8 h;
#pragma unroll
            for (int i = 0; i < 8; ++i) h[i] = (_Float16)vb[i][j];
            *(half8*)&Bs[(sm0 + j) * 64 + ((skq ^ ((sm0 + j) & 7)) << 3)] = h;
        }
        __syncthreads();
        // issue next tile's loads (hide HBM latency under MFMA phase)
        if (k0 + 64 < 2048) {
            const long kn = k0 + 64;
#pragma unroll
            for (int i = 0; i < 8; ++i)
                va[i] = *(const f32x4*)(Ab + (kn + skq * 8 + i) * 1024 + sm0);
#pragma unroll
            for (int i = 0; i < 8; ++i)
                vb[i] = *(const f32x4*)(Bb + (kn + skq * 8 + i) * 256 + sm0);
        }
#pragma unroll
        for (int kh = 0; kh < 2; ++kh) {
            const int c = (((kh * 4) + kq) ^ rs) * 8;
            half8 af[4], bf[4];
#pragma unroll
            for (int i = 0; i < 4; ++i) {
                af[i] = *(const half8*)&As[(wm + i * 16 + lr) * 64 + c];
                bf[i] = *(const half8*)&Bs[(wn + i * 16 + lr) * 64 + c];
            }
#pragma unroll
            for (int i = 0; i < 4; ++i)
#pragma unroll
                for (int j = 0; j < 4; ++j)
                    acc[i][j] = __builtin_amdgcn_mfma_f32_16x16x32_f16(af[i], bf[j], acc[i][j], 0, 0, 0);
        }
        __syncthreads();
    }

    // transposed store: math C[m=e][n=kk] -> memory [kk][e]; acc[i][j] holds
    // rows crow+i*16+0..3 (contiguous) for col ccol+j*16 -> one f32x4 store.
    const int crow = mb * 128 + wm + (kq << 2);   // e
    const int ccol = nb * 128 + wn + lr;          // kk
#pragma unroll
    for (int i = 0; i < 4; ++i)
#pragma unroll
        for (int j = 0; j < 4; ++j)
            *(f32x4*)&Cb[(long)(ccol + j * 16) * 1024 + crow + i * 16] = acc[i][j];
}

// Pkv[b][kk][e] = f16( P32[0][b][kk][e] + P32[1][b][kk][e] )  (flat layouts match)
__global__ void reduce_kv2(const float* __restrict__ P, _Float16* __restrict__ Pkv) {
    const long o = ((long)blockIdx.x * 256 + threadIdx.x) * 4;
    float4 a = *(const float4*)(P + o);
    float4 bb = *(const float4*)(P + o + 4194304);
    half4 out;
    out[0] = (_Float16)(a.x + bb.x); out[1] = (_Float16)(a.y + bb.y);
    out[2] = (_Float16)(a.z + bb.z); out[3] = (_Float16)(a.w + bb.w);
    *(half4*)(Pkv + o) = out;
}

// ---------------------------------------------------------------------------
// Fused scores+softmax: wts[b][l][kk] = softmax_kk( x[b][l]:Mt[b][kk] + cb[b][kk] )
// Block = 128 rows x 256 cols. A = x fp32 (reg-staged f16 convert, R9);
// B = Mt f16 via global_load_lds.
// ---------------------------------------------------------------------------
__global__ __launch_bounds__(256) void score_softmax(
    const float* __restrict__ X, const _Float16* __restrict__ Bm,
    const float* __restrict__ cb, _Float16* __restrict__ Wts)
{
    const int b = blockIdx.z, mb = blockIdx.x;
    const float* Ab = X + (long)b * 4194304 + (long)mb * 131072;
    const _Float16* Bb = Bm + (long)b * 262144;
    const int tid = threadIdx.x, w = tid >> 6, ln = tid & 63;
    const int lr = ln & 15, rs = ln & 7, kq = ln >> 4;

    __shared__ __attribute__((aligned(16))) _Float16 SM[24576]; // As 8192 | Bs 16384
    _Float16* As = SM;
    _Float16* Bs = SM + 8192;

    f32x4 acc[2][16] = {};

    for (int k0 = 0; k0 < 1024; k0 += 64) {
        f32x4 pa[4][2];
#pragma unroll
        for (int t = 0; t < 4; ++t) {           // A-tile loads: 128x64 fp32
            const int ci = w * 256 + t * 64 + ln;
            const int r = ci >> 3, kc = (ci & 7) ^ (r & 7);
            const float* ap = Ab + (long)r * 1024 + k0 + kc * 8;
            pa[t][0] = *(const f32x4*)ap;
            pa[t][1] = *(const f32x4*)(ap + 4);
        }
#pragma unroll
        for (int t = 0; t < 8; ++t) {           // B-tile: 256x64 f16 via gld_lds
            const int cbase = w * 512 + t * 64;
            const int ci = cbase + ln, r = ci >> 3, kc = (ci & 7) ^ (r & 7);
            gld_lds16(Bb + (long)r * 1024 + k0 + kc * 8, &Bs[cbase * 8]);
        }
#pragma unroll
        for (int t = 0; t < 4; ++t) {           // A-tile writes (cvt f16)
            const int ci = w * 256 + t * 64 + ln;
            *(half8*)&As[ci * 8] = cvt_h8(pa[t][0], pa[t][1]);
        }
        __syncthreads();
#pragma unroll
        for (int kh = 0; kh < 2; ++kh) {
            const int c = (((kh * 4) + kq) ^ rs) * 8;
            const half8 af0 = *(const half8*)&As[(w * 32 + lr) * 64 + c];
            const half8 af1 = *(const half8*)&As[(w * 32 + 16 + lr) * 64 + c];
#pragma unroll
            for (int j = 0; j < 16; ++j) {
                const half8 bf = *(const half8*)&Bs[(j * 16 + lr) * 64 + c];
                acc[0][j] = __builtin_amdgcn_mfma_f32_16x16x32_f16(af0, bf, acc[0][j], 0, 0, 0);
                acc[1][j] = __builtin_amdgcn_mfma_f32_16x16x32_f16(af1, bf, acc[1][j], 0, 0, 0);
            }
        }
        __syncthreads();
    }

    // lane holds rows (w*32 + i*16 + kq*4 + r), cols (j*16 + lr)
    float cbl[16];
    const float* cbb = cb + b * 256;
#pragma unroll
    for (int j = 0; j < 16; ++j) cbl[j] = cbb[j * 16 + lr];

#pragma unroll
    for (int i = 0; i < 2; ++i)
#pragma unroll
        for (int r = 0; r < 4; ++r) {
            float m = -3.0e38f;
#pragma unroll
            for (int j = 0; j < 16; ++j) {
                float v = acc[i][j][r] + cbl[j];
                acc[i][j][r] = v;
                m = fmaxf(m, v);
            }
            m = fmaxf(m, __shfl_xor(m, 1, 64)); m = fmaxf(m, __shfl_xor(m, 2, 64));
            m = fmaxf(m, __shfl_xor(m, 4, 64)); m = fmaxf(m, __shfl_xor(m, 8, 64));
            float s = 0.f;
#pragma unroll
            for (int j = 0; j < 16; ++j) {
                float e = __expf(acc[i][j][r] - m);
                acc[i][j][r] = e;
                s += e;
            }
            s += __shfl_xor(s, 1, 64); s += __shfl_xor(s, 2, 64);
            s += __shfl_xor(s, 4, 64); s += __shfl_xor(s, 8, 64);
            const float inv = 1.0f / s;
#pragma unroll
            for (int j = 0; j < 16; ++j) acc[i][j][r] *= inv;
        }

    // pack 64-row halves through LDS (pitch 264: 16B-aligned rows, kq->bank spread)
#pragma unroll
    for (int i = 0; i < 2; ++i) {
        __syncthreads();
#pragma unroll
        for (int r = 0; r < 4; ++r)
#pragma unroll
            for (int j = 0; j < 16; ++j)
                SM[(w * 16 + kq * 4 + r) * 264 + j * 16 + lr] = (_Float16)acc[i][j][r];
        __syncthreads();
#pragma unroll
        for (int u = 0; u < 8; ++u) {
            const int idx = tid + 256 * u, row = idx >> 5, ci2 = idx & 31;
            const half8 v = *(const half8*)&SM[row * 264 + ci2 * 8];
            const long grow = (long)b * 4096 + mb * 128 + (row >> 4) * 32 + i * 16 + (row & 15);
            *(half8*)&Wts[grow * 256 + ci2 * 8] = v;
        }
    }
}

// ---------------------------------------------------------------------------
// 64x64-tile transpose+convert: src fp32 [R][C] -> dst f16 [C][R];
// optionally straight f16 copy dsth (layout of src). Batched via blockIdx.z.
// Pitch-65 LDS (2-way max aliasing, free); half8 (16B) transposed stores.
// (R10: only the Wq transpose remains.)
// ---------------------------------------------------------------------------
__global__ __launch_bounds__(256) void tr64(const float* __restrict__ src,
                                            _Float16* __restrict__ dst,
                                            _Float16* __restrict__ dsth,
                                            int R, int C, long sbatch, long dbatch) {
    __shared__ float T[64 * 65];
    const float* s = src + (long)blockIdx.z * sbatch;
    _Float16* d = dst + (long)blockIdx.z * dbatch;
    _Float16* dh = dsth ? dsth + (long)blockIdx.z * sbatch : nullptr;
    const int c0 = blockIdx.x * 64, r0 = blockIdx.y * 64;
    const int t = threadIdx.x;
    {
        const int row = t >> 2, cp = (t & 3) * 16;
        const float* sp = s + (long)(r0 + row) * C + c0 + cp;
        const float4 v0 = *(const float4*)(sp + 0);
        const float4 v1 = *(const float4*)(sp + 4);
        const float4 v2 = *(const float4*)(sp + 8);
        const float4 v3 = *(const float4*)(sp + 12);
        float* Tr = &T[row * 65 + cp];
        Tr[ 0] = v0.x; Tr[ 1] = v0.y; Tr[ 2] = v0.z; Tr[ 3] = v0.w;
        Tr[ 4] = v1.x; Tr[ 5] = v1.y; Tr[ 6] = v1.z; Tr[ 7] = v1.w;
        Tr[ 8] = v2.x; Tr[ 9] = v2.y; Tr[10] = v2.z; Tr[11] = v2.w;
        Tr[12] = v3.x; Tr[13] = v3.y; Tr[14] = v3.z; Tr[15] = v3.w;
        if (dh) {
            half8 h0, h1;
            h0[0] = (_Float16)v0.x; h0[1] = (_Float16)v0.y;
            h0[2] = (_Float16)v0.z; h0[3] = (_Float16)v0.w;
            h0[4] = (_Float16)v1.x; h0[5] = (_Float16)v1.y;
            h0[6] = (_Float16)v1.z; h0[7] = (_Float16)v1.w;
            h1[0] = (_Float16)v2.x; h1[1] = (_Float16)v2.y;
            h1[2] = (_Float16)v2.z; h1[3] = (_Float16)v2.w;
            h1[4] = (_Float16)v3.x; h1[5] = (_Float16)v3.y;
            h1[6] = (_Float16)v3.z; h1[7] = (_Float16)v3.w;
            _Float16* dp = dh + (long)(r0 + row) * C + c0 + cp;
            *(half8*)(dp + 0) = h0;
            *(half8*)(dp + 8) = h1;
        }
    }
    __syncthreads();
    {
        const int qq = t & 7, cc = t >> 3;
#pragma unroll
        for (int it = 0; it < 2; ++it) {
            const int col = cc + it * 32;
            half8 o;
#pragma unroll
            for (int u = 0; u < 8; ++u) o[u] = (_Float16)T[(qq * 8 + u) * 65 + col];
            *(half8*)(d + (long)(c0 + col) * R + r0 + qq * 8) = o;
        }
    }
}

// column sums of Hk and Hv (each [4096][256]) -> sk[256], sv[256]
__global__ void colsum2(const float* __restrict__ Hk, const float* __restrict__ Hv,
                        float* __restrict__ sk, float* __restrict__ sv) {
    const float* H = blockIdx.y ? Hv : Hk;
    float* s = blockIdx.y ? sv : sk;
    const int c = threadIdx.x;
    const long r0 = (long)blockIdx.x * 64;
    float acc = 0.f;
    for (int r = 0; r < 64; ++r) acc += H[(r0 + r) * 256 + c];
    atomicAdd(s + c, acc);
}

// g[c]=bq.Wk[c,:]/32 ; h[e]=bk.Wq[e,:]/32 ; gh[2048]=bq.bk/32  (one wave each)
__global__ void bias_vecs(const float* __restrict__ W, const float* __restrict__ b,
                          float* __restrict__ gh) {
    const int wid = blockIdx.x * 4 + (threadIdx.x >> 6);
    const int ln = threadIdx.x & 63;
    float acc = 0.f;
    if (wid < 1024) {
        for (int j = 0; j < 16; ++j) { int d = ln + 64 * j; acc += b[d] * W[(long)wid * 3072 + 1024 + d]; }
    } else if (wid < 2048) {
        for (int j = 0; j < 16; ++j) { int d = ln + 64 * j; acc += b[1024 + d] * W[(long)(wid - 1024) * 3072 + d]; }
    } else if (wid == 2048) {
        for (int j = 0; j < 16; ++j) { int d = ln + 64 * j; acc += b[d] * b[1024 + d]; }
    } else return;
#pragma unroll
    for (int o = 32; o > 0; o >>= 1) acc += __shfl_xor(acc, o, 64);
    if (!ln) gh[wid] = acc * 0.03125f;
}

// cb[b*256+kk] = sum_c Pk[b][kk][c]*g[c] + sk[kk]*gh[2048]   (one wave each)
// Pkv layout [8 b][512 (k|v)][1024] -> k-row of (b,kk) at b*524288 + kk*1024.
__global__ void cb_kernel(const _Float16* __restrict__ Pk, const float* __restrict__ gh,
                          const float* __restrict__ sk, float* __restrict__ cb) {
    const int wid = blockIdx.x * 4 + (threadIdx.x >> 6);
    const int ln = threadIdx.x & 63;
    const _Float16* row = Pk + (long)(wid >> 8) * 524288 + (long)(wid & 255) * 1024;
    float acc = 0.f;
    for (int j = 0; j < 16; ++j) { int c = ln + 64 * j; acc += (float)row[c] * gh[c]; }
#pragma unroll
    for (int o = 32; o > 0; o >>= 1) acc += __shfl_xor(acc, o, 64);
    if (!ln) cb[wid] = acc + sk[wid & 255] * gh[2048];
}

extern "C" void kernel_launch(void* const* d_in, const int* in_sizes, int n_in,
                              void* d_out, int out_size, void* d_ws, size_t ws_size,
                              hipStream_t stream) {
    const float* x    = (const float*)d_in[0]; // [8,4096,1024]
    const float* Wq   = (const float*)d_in[1]; // [1024,3072]
    const float* bqkv = (const float*)d_in[2]; // [3072]
    const float* Hk   = (const float*)d_in[3]; // [4096,256]
    const float* Hv   = (const float*)d_in[4]; // [4096,256]
    float* out = (float*)d_out;                // [8,4096,1024]

    char* p = (char*)d_ws;
    auto take = [&](size_t n) { char* r = p; p += (n + 255) & ~(size_t)255; return r; };
    _Float16* Wt  = (_Float16*)take(3145728ull * 2);  // W^T f16 [3072][1024]
    _Float16* Wh  = (_Float16*)take(3145728ull * 2);  // W f16 [1024][3072]
    _Float16* Pkv = (_Float16*)take(4194304ull * 2);  // [8 b][512 (k|v)][1024 e]
    _Float16* VpT = (_Float16*)take(2097152ull * 2);  // V_proj^T [8][1024][256]
    _Float16* Gt  = (_Float16*)take(1048576ull * 2);  // [1024 d][1024 c]
    _Float16* Mt  = (_Float16*)take(2097152ull * 2);  // [8][256][1024]
    float*    gh  = (float*)take(2049 * 4);           // g[1024] ++ h[1024] ++ bq.bk/32
    float*    sk  = (float*)take(512 * 4);            // sk[256] ++ sv[256]
    float*    sv  = sk + 256;
    float*    cbv = (float*)take(2048 * 4);           // score bias per (b,kk)
    float*    P32 = (float*)take(8388608ull * 4);     // [2ks][8b][512][1024]
    _Float16* wts = (_Float16*)take(8388608ull * 2);  // softmax weights f16

    const dim3 B256(256);

    // --- input prep (R10: only the W transpose remains) ---
    tr64<<<dim3(48, 16, 1), B256, 0, stream>>>(Wq, Wt, Wh, 1024, 3072, 0, 0);
    hipMemsetAsync(sk, 0, 512 * 4, stream);
    colsum2<<<dim3(64, 2, 1), B256, 0, stream>>>(Hk, Hv, sk, sv);
    bias_vecs<<<513, B256, 0, stream>>>(Wq, bqkv, gh);

    // --- P32[ks][b][kk][e] = sum_l x.H (tn, native fp32, K-split 2x2048) ---
    gemm_tn_pkv<<<dim3(32, 1, 16), B256, 0, stream>>>(x, Hk, Hv, P32);
    reduce_kv2<<<4096, B256, 0, stream>>>(P32, Pkv);

    // --- Gt[d][c] = sum_e W[d][e]*W[c][1024+e] : K=1024 ---
    gemm_bt<_Float16, true><<<dim3(64, 1, 1), B256, 0, stream>>>(
        Wh, 0, 0, 0, 3072, Wh + 1024, 0, 0, 0, 3072, Gt, 0, 0, 0, 1024,
        1, 1, 8, 8, 1024, nullptr, 0, nullptr, nullptr, 1.0f);
    // --- V_proj^T = Wv^T Pv^T + bv (x) sv : [8][1024][256], K=1024 ---
    gemm_bt<_Float16, true><<<dim3(16, 1, 8), B256, 0, stream>>>(
        Wt + 2097152, 0, 0, 0, 1024, Pkv + 262144, 524288, 0, 0, 1024,
        VpT, 262144, 0, 0, 256,
        8, 1, 8, 2, 1024, nullptr, 0, bqkv + 2048, sv, 1.0f);
    // --- Mt = Pk*Gt^T/32 + sk (x) h : [8][256][1024], K=1024 ---
    gemm_bt<_Float16, false><<<dim3(16, 1, 8), B256, 0, stream>>>(
        Pkv, 524288, 0, 0, 1024, Gt, 0, 0, 0, 1024,
        Mt, 262144, 0, 0, 1024,
        8, 1, 2, 8, 1024, nullptr, 0, sk, gh + 1024, 0.03125f);
    // --- cb[b][kk] = Pk.g + sk*(bq.bk)  (already /32) ---
    cb_kernel<<<512, B256, 0, stream>>>(Pkv, gh, sk, cbv);
    // --- fused scores+softmax -> wts f16 [8][4096][256] (A = x fp32) ---
    score_softmax<<<dim3(32, 1, 8), B256, 0, stream>>>(x, Mt, cbv, wts);
    // --- out = weights V_proj : fp32 [8][4096][1024], K=256 (NT stores) ---
    gemm_bt<float, true><<<dim3(256, 1, 8), B256, 0, stream>>>(
        wts, 1048576, 0, 0, 256, VpT, 262144, 0, 0, 256,
        out, 4194304, 0, 0, 1024,
        8, 1, 32, 8, 256, nullptr, 0, nullptr, nullptr, 1.0f);
}